// Round 1
// baseline (353.560 us; speedup 1.0000x reference)
//
#include <hip/hip_runtime.h>
#include <hip/hip_bf16.h>
#include <stdint.h>

#define D_MODEL 1024
#define SEQ 2048
#define BATCH 4
#define NHEADS 16
#define ROWS (BATCH*SEQ)   // 8192

typedef __attribute__((ext_vector_type(4))) float f32x4;
typedef __attribute__((ext_vector_type(8))) short short8;

__device__ __forceinline__ unsigned short f2bf(float f) {
    unsigned int x = __builtin_bit_cast(unsigned int, f);
    x += 0x7fffu + ((x >> 16) & 1u);   // RNE
    return (unsigned short)(x >> 16);
}

// ---------- weight transpose + f32->bf16: wt[n][k] = bf16(w[k][n]) ----------
__global__ __launch_bounds__(256) void wtrans_kernel(const float* __restrict__ w,
                                                     unsigned short* __restrict__ wt) {
    __shared__ float tile[32][33];
    int tx = threadIdx.x & 31;
    int ty = threadIdx.x >> 5;           // 0..7
    int r0 = blockIdx.y * 32, c0 = blockIdx.x * 32;
    #pragma unroll
    for (int i = 0; i < 4; ++i)
        tile[ty + 8*i][tx] = w[(size_t)(r0 + ty + 8*i) * D_MODEL + (c0 + tx)];
    __syncthreads();
    #pragma unroll
    for (int i = 0; i < 4; ++i)
        wt[(size_t)(c0 + ty + 8*i) * D_MODEL + (r0 + tx)] = f2bf(tile[tx][ty + 8*i]);
}

// ---------- GEMM: C[8192x1024] = A[8192x1024] * Bt^T (+bias) ----------
// Bt is [N][K] bf16 (row n = column n of W).  AF32: A is f32, convert while
// staging.  OUTHEAD: write bf16 into [B][H][S][64] head layout, else f32
// row-major to d_out.
template<int AF32, int OUTHEAD>
__global__ __launch_bounds__(256) void gemm_kernel(const void* __restrict__ Aptr,
                                                   const unsigned short* __restrict__ Bt,
                                                   const float* __restrict__ bias,
                                                   void* __restrict__ Out) {
    __shared__ unsigned short Alds[128*64];   // [row][k] bf16, XOR-swizzled
    __shared__ unsigned short Blds[128*64];
    const int m0 = blockIdx.x * 128;
    const int n0 = blockIdx.y * 128;
    const int t = threadIdx.x;
    const int lane = t & 63;
    const int w = t >> 6;
    const int wm = w >> 1, wn = w & 1;        // 2x2 wave grid, 64x64 each
    const int l15 = lane & 15, lg = lane >> 4;

    f32x4 acc[4][4];
    #pragma unroll
    for (int i = 0; i < 4; ++i)
        #pragma unroll
        for (int j = 0; j < 4; ++j) acc[i][j] = (f32x4)(0.0f);

    for (int k0 = 0; k0 < D_MODEL; k0 += 64) {
        if (AF32) {
            const float* Af = (const float*)Aptr;
            #pragma unroll
            for (int i = 0; i < 8; ++i) {
                int idx = t + i*256;           // 0..2047, 16 float4 per row
                int row = idx >> 4, c4 = idx & 15;
                f32x4 v = *(const f32x4*)(Af + (size_t)(m0+row)*D_MODEL + k0 + c4*4);
                unsigned long long pk = (unsigned long long)f2bf(v[0])
                    | ((unsigned long long)f2bf(v[1]) << 16)
                    | ((unsigned long long)f2bf(v[2]) << 32)
                    | ((unsigned long long)f2bf(v[3]) << 48);
                int byte = (row*128 + c4*8) ^ ((row & 7) << 4);
                *(unsigned long long*)((char*)Alds + byte) = pk;
            }
        } else {
            const unsigned short* Ab = (const unsigned short*)Aptr;
            #pragma unroll
            for (int i = 0; i < 4; ++i) {
                int idx = t + i*256;           // 0..1023, 8 chunks per row
                int row = idx >> 3, c8 = idx & 7;
                short8 v = *(const short8*)(Ab + (size_t)(m0+row)*D_MODEL + k0 + c8*8);
                int byte = (row*128 + c8*16) ^ ((row & 7) << 4);
                *(short8*)((char*)Alds + byte) = v;
            }
        }
        #pragma unroll
        for (int i = 0; i < 4; ++i) {
            int idx = t + i*256;
            int row = idx >> 3, c8 = idx & 7;
            short8 v = *(const short8*)(Bt + (size_t)(n0+row)*D_MODEL + k0 + c8*8);
            int byte = (row*128 + c8*16) ^ ((row & 7) << 4);
            *(short8*)((char*)Blds + byte) = v;
        }
        __syncthreads();

        #pragma unroll
        for (int kk = 0; kk < 2; ++kk) {
            short8 af[4], bfr[4];
            #pragma unroll
            for (int mi = 0; mi < 4; ++mi) {
                int row = wm*64 + mi*16 + l15;
                int byte = (row*128 + kk*64 + lg*16) ^ ((row & 7) << 4);
                af[mi] = *(const short8*)((const char*)Alds + byte);
            }
            #pragma unroll
            for (int ni = 0; ni < 4; ++ni) {
                int row = wn*64 + ni*16 + l15;
                int byte = (row*128 + kk*64 + lg*16) ^ ((row & 7) << 4);
                bfr[ni] = *(const short8*)((const char*)Blds + byte);
            }
            #pragma unroll
            for (int mi = 0; mi < 4; ++mi)
                #pragma unroll
                for (int ni = 0; ni < 4; ++ni)
                    acc[mi][ni] = __builtin_amdgcn_mfma_f32_16x16x32_bf16(
                        af[mi], bfr[ni], acc[mi][ni], 0, 0, 0);
        }
        __syncthreads();
    }

    // epilogue: C/D layout col = lane&15, row = (lane>>4)*4 + reg
    #pragma unroll
    for (int mi = 0; mi < 4; ++mi)
        #pragma unroll
        for (int ni = 0; ni < 4; ++ni) {
            int col = n0 + wn*64 + ni*16 + l15;
            float bv = bias[col];
            #pragma unroll
            for (int r = 0; r < 4; ++r) {
                int row = m0 + wm*64 + mi*16 + lg*4 + r;
                float v = acc[mi][ni][r] + bv;
                if (OUTHEAD) {
                    int bb = row >> 11, s = row & 2047;     // row = b*2048+s
                    int h = col >> 6, d = col & 63;         // col = h*64+d
                    ((unsigned short*)Out)[(((size_t)(bb*NHEADS + h)*SEQ + s) << 6) + d] = f2bf(v);
                } else {
                    ((float*)Out)[(size_t)row*D_MODEL + col] = v;
                }
            }
        }
}

// ---------- flash attention: per block = one (b,h), 64 q rows, 4 waves ----------
__global__ __launch_bounds__(256) void attn_kernel(const unsigned short* __restrict__ qh,
                                                   const unsigned short* __restrict__ kh,
                                                   const unsigned short* __restrict__ vh,
                                                   unsigned short* __restrict__ xout) {
    __shared__ unsigned short Klds[64*64];       // [kv][d] swizzled
    __shared__ unsigned short Vt[64*64];         // [d][kv] swizzled
    __shared__ unsigned short Plds[4][16][72];   // per-wave P, +8 pad

    const int qb = blockIdx.x;     // 0..31
    const int bh = blockIdx.y;     // 0..63
    const int t = threadIdx.x;
    const int lane = t & 63;
    const int w = t >> 6;
    const int l15 = lane & 15, lg = lane >> 4;

    const unsigned short* qbase = qh + (size_t)bh * SEQ * 64;
    const unsigned short* kbase = kh + (size_t)bh * SEQ * 64;
    const unsigned short* vbase = vh + (size_t)bh * SEQ * 64;

    // Q fragments hoisted: wave w owns q rows qb*64+w*16 .. +15
    const int qrow = qb*64 + w*16 + l15;
    short8 qf0 = *(const short8*)(qbase + (size_t)qrow*64 + lg*8);
    short8 qf1 = *(const short8*)(qbase + (size_t)qrow*64 + 32 + lg*8);

    float m[4], lsum[4];
    f32x4 o[4];                                   // o[nb]: d group nb*16+l15
    #pragma unroll
    for (int r = 0; r < 4; ++r) { m[r] = -3e38f; lsum[r] = 0.f; }
    #pragma unroll
    for (int nb = 0; nb < 4; ++nb) o[nb] = (f32x4)(0.0f);

    for (int kv0 = 0; kv0 < SEQ; kv0 += 64) {
        // stage K [64][64] swizzled
        #pragma unroll
        for (int i = 0; i < 2; ++i) {
            int idx = t + i*256;
            int row = idx >> 3, c8 = idx & 7;
            short8 v = *(const short8*)(kbase + (size_t)(kv0+row)*64 + c8*8);
            int byte = (row*128 + c8*16) ^ ((row & 7) << 4);
            *(short8*)((char*)Klds + byte) = v;
        }
        // stage V transposed: Vt[d][kv], packed 2 kv per u32 write
        {
            int rp = t & 31, c8 = t >> 5;
            short8 v0 = *(const short8*)(vbase + (size_t)(kv0 + 2*rp)*64 + c8*8);
            short8 v1 = *(const short8*)(vbase + (size_t)(kv0 + 2*rp + 1)*64 + c8*8);
            #pragma unroll
            for (int j = 0; j < 8; ++j) {
                int d = c8*8 + j;
                unsigned int pk = (unsigned int)(unsigned short)v0[j]
                                | ((unsigned int)(unsigned short)v1[j] << 16);
                int byte = (d*128 + rp*4) ^ ((d & 7) << 4);
                *(unsigned int*)((char*)Vt + byte) = pk;
            }
        }
        __syncthreads();

        // S = Q K^T : D col = kv (l15), row = q (lg*4+reg)
        f32x4 sa[4];
        #pragma unroll
        for (int nb = 0; nb < 4; ++nb) {
            int krow = nb*16 + l15;
            int b0 = (krow*128 + lg*16) ^ ((krow & 7) << 4);
            int b1 = (krow*128 + 64 + lg*16) ^ ((krow & 7) << 4);
            short8 kf0 = *(const short8*)((const char*)Klds + b0);
            short8 kf1 = *(const short8*)((const char*)Klds + b1);
            f32x4 s = (f32x4)(0.0f);
            s = __builtin_amdgcn_mfma_f32_16x16x32_bf16(qf0, kf0, s, 0, 0, 0);
            s = __builtin_amdgcn_mfma_f32_16x16x32_bf16(qf1, kf1, s, 0, 0, 0);
            sa[nb] = s;
        }

        // online softmax per q row r (16 kv vals per nb live in lanes of same lg)
        #pragma unroll
        for (int r = 0; r < 4; ++r) {
            float s0 = sa[0][r]*0.125f, s1 = sa[1][r]*0.125f;
            float s2 = sa[2][r]*0.125f, s3 = sa[3][r]*0.125f;
            float tm = fmaxf(fmaxf(s0, s1), fmaxf(s2, s3));
            tm = fmaxf(tm, __shfl_xor(tm, 1));
            tm = fmaxf(tm, __shfl_xor(tm, 2));
            tm = fmaxf(tm, __shfl_xor(tm, 4));
            tm = fmaxf(tm, __shfl_xor(tm, 8));
            float mnew = fmaxf(m[r], tm);
            float p0 = __expf(s0 - mnew), p1 = __expf(s1 - mnew);
            float p2 = __expf(s2 - mnew), p3 = __expf(s3 - mnew);
            float ts = p0 + p1 + p2 + p3;
            ts += __shfl_xor(ts, 1);
            ts += __shfl_xor(ts, 2);
            ts += __shfl_xor(ts, 4);
            ts += __shfl_xor(ts, 8);
            float alpha = __expf(m[r] - mnew);
            lsum[r] = lsum[r]*alpha + ts;
            m[r] = mnew;
            #pragma unroll
            for (int nb = 0; nb < 4; ++nb) o[nb][r] *= alpha;
            int prow = lg*4 + r;
            Plds[w][prow][l15]      = f2bf(p0);
            Plds[w][prow][16 + l15] = f2bf(p1);
            Plds[w][prow][32 + l15] = f2bf(p2);
            Plds[w][prow][48 + l15] = f2bf(p3);
        }

        // O += P V : A = P (row q = l15, kv k-contig), B = Vt rows (col d = l15)
        #pragma unroll
        for (int kk = 0; kk < 2; ++kk) {
            short8 pa = *(const short8*)(&Plds[w][l15][kk*32 + lg*8]);
            #pragma unroll
            for (int nb = 0; nb < 4; ++nb) {
                int vrow = nb*16 + l15;
                int byte = (vrow*128 + kk*64 + lg*16) ^ ((vrow & 7) << 4);
                short8 vf = *(const short8*)((const char*)Vt + byte);
                o[nb] = __builtin_amdgcn_mfma_f32_16x16x32_bf16(pa, vf, o[nb], 0, 0, 0);
            }
        }
        __syncthreads();
    }

    // epilogue: x[b][s][h*64+d] bf16
    const int bb = bh >> 4, h = bh & 15;
    #pragma unroll
    for (int nb = 0; nb < 4; ++nb)
        #pragma unroll
        for (int r = 0; r < 4; ++r) {
            int s = qb*64 + w*16 + lg*4 + r;
            int d = nb*16 + l15;
            float v = o[nb][r] / lsum[r];
            xout[((size_t)(bb*SEQ + s))*D_MODEL + h*64 + d] = f2bf(v);
        }
}

extern "C" void kernel_launch(void* const* d_in, const int* in_sizes, int n_in,
                              void* d_out, int out_size, void* d_ws, size_t ws_size,
                              hipStream_t stream) {
    (void)in_sizes; (void)n_in; (void)out_size; (void)ws_size;
    const float* q  = (const float*)d_in[0];
    const float* k  = (const float*)d_in[1];
    const float* v  = (const float*)d_in[2];
    const float* wq = (const float*)d_in[3];
    const float* bq = (const float*)d_in[4];
    const float* wk = (const float*)d_in[5];
    const float* bk = (const float*)d_in[6];
    const float* wv = (const float*)d_in[7];
    const float* bv = (const float*)d_in[8];
    const float* wo = (const float*)d_in[9];
    const float* bo = (const float*)d_in[10];

    // workspace layout (72 MB total)
    char* ws = (char*)d_ws;
    unsigned short* wqt = (unsigned short*)(ws);                    // 2 MB each
    unsigned short* wkt = (unsigned short*)(ws + (2ull << 20));
    unsigned short* wvt = (unsigned short*)(ws + (4ull << 20));
    unsigned short* wot = (unsigned short*)(ws + (6ull << 20));
    unsigned short* qhd = (unsigned short*)(ws + (8ull << 20));     // 16 MB each
    unsigned short* khd = (unsigned short*)(ws + (24ull << 20));
    unsigned short* vhd = (unsigned short*)(ws + (40ull << 20));
    unsigned short* xat = (unsigned short*)(ws + (56ull << 20));

    dim3 tgrid(D_MODEL/32, D_MODEL/32);
    hipLaunchKernelGGL(wtrans_kernel, tgrid, dim3(256), 0, stream, wq, wqt);
    hipLaunchKernelGGL(wtrans_kernel, tgrid, dim3(256), 0, stream, wk, wkt);
    hipLaunchKernelGGL(wtrans_kernel, tgrid, dim3(256), 0, stream, wv, wvt);
    hipLaunchKernelGGL(wtrans_kernel, tgrid, dim3(256), 0, stream, wo, wot);

    dim3 ggrid(ROWS/128, D_MODEL/128);
    hipLaunchKernelGGL((gemm_kernel<1,1>), ggrid, dim3(256), 0, stream,
                       (const void*)q, wqt, bq, (void*)qhd);
    hipLaunchKernelGGL((gemm_kernel<1,1>), ggrid, dim3(256), 0, stream,
                       (const void*)k, wkt, bk, (void*)khd);
    hipLaunchKernelGGL((gemm_kernel<1,1>), ggrid, dim3(256), 0, stream,
                       (const void*)v, wvt, bv, (void*)vhd);

    hipLaunchKernelGGL(attn_kernel, dim3(SEQ/64, BATCH*NHEADS), dim3(256), 0, stream,
                       qhd, khd, vhd, xat);

    hipLaunchKernelGGL((gemm_kernel<0,0>), ggrid, dim3(256), 0, stream,
                       (const void*)xat, wot, bo, d_out);
}

// Round 2
// 297.899 us; speedup vs baseline: 1.1868x; 1.1868x over previous
//
#include <hip/hip_runtime.h>
#include <hip/hip_bf16.h>
#include <stdint.h>

#define D_MODEL 1024
#define SEQ 2048
#define BATCH 4
#define NHEADS 16
#define ROWS (BATCH*SEQ)   // 8192

typedef __attribute__((ext_vector_type(4))) float f32x4;
typedef __attribute__((ext_vector_type(8))) short short8;

__device__ __forceinline__ unsigned short f2bf(float f) {
    unsigned int x = __builtin_bit_cast(unsigned int, f);
    x += 0x7fffu + ((x >> 16) & 1u);   // RNE
    return (unsigned short)(x >> 16);
}

// ---------- weight transpose + f32->bf16: wt[n][k] = bf16(w[k][n]) ----------
__global__ __launch_bounds__(256) void wtrans_kernel(const float* __restrict__ w,
                                                     unsigned short* __restrict__ wt) {
    __shared__ float tile[32][33];
    int tx = threadIdx.x & 31;
    int ty = threadIdx.x >> 5;           // 0..7
    int r0 = blockIdx.y * 32, c0 = blockIdx.x * 32;
    #pragma unroll
    for (int i = 0; i < 4; ++i)
        tile[ty + 8*i][tx] = w[(size_t)(r0 + ty + 8*i) * D_MODEL + (c0 + tx)];
    __syncthreads();
    #pragma unroll
    for (int i = 0; i < 4; ++i)
        wt[(size_t)(c0 + ty + 8*i) * D_MODEL + (r0 + tx)] = f2bf(tile[tx][ty + 8*i]);
}

// ---------- GEMM: C[8192x1024] = A[8192x1024] * Bt^T (+bias) ----------
// Bt is [N][K] bf16.  AF32: A is f32 (convert while staging).
// OUTMODE 0: f32 row-major.  1: bf16 head layout [b,h,s,64].
//         2: bf16 TRANSPOSED head layout [b,h,64,s] (for V).
// QSCALE: multiply output by 0.125 (fold 1/sqrt(d_k) into Q projection).
template<int AF32, int OUTMODE, int QSCALE>
__global__ __launch_bounds__(256) void gemm_kernel(const void* __restrict__ Aptr,
                                                   const unsigned short* __restrict__ Bt,
                                                   const float* __restrict__ bias,
                                                   void* __restrict__ Out) {
    __shared__ __attribute__((aligned(16))) unsigned short Alds[128*64];
    __shared__ __attribute__((aligned(16))) unsigned short Blds[128*64];
    const int m0 = blockIdx.x * 128;
    const int n0 = blockIdx.y * 128;
    const int t = threadIdx.x;
    const int lane = t & 63;
    const int w = t >> 6;
    const int wm = w >> 1, wn = w & 1;        // 2x2 wave grid, 64x64 each
    const int l15 = lane & 15, lg = lane >> 4;

    f32x4 acc[4][4];
    #pragma unroll
    for (int i = 0; i < 4; ++i)
        #pragma unroll
        for (int j = 0; j < 4; ++j) acc[i][j] = (f32x4)(0.0f);

    for (int k0 = 0; k0 < D_MODEL; k0 += 64) {
        if (AF32) {
            const float* Af = (const float*)Aptr;
            #pragma unroll
            for (int i = 0; i < 8; ++i) {
                int idx = t + i*256;           // 0..2047, 16 float4 per row
                int row = idx >> 4, c4 = idx & 15;
                f32x4 v = *(const f32x4*)(Af + (size_t)(m0+row)*D_MODEL + k0 + c4*4);
                unsigned long long pk = (unsigned long long)f2bf(v[0])
                    | ((unsigned long long)f2bf(v[1]) << 16)
                    | ((unsigned long long)f2bf(v[2]) << 32)
                    | ((unsigned long long)f2bf(v[3]) << 48);
                int byte = (row*128 + c4*8) ^ ((row & 7) << 4);
                *(unsigned long long*)((char*)Alds + byte) = pk;
            }
        } else {
            const unsigned short* Ab = (const unsigned short*)Aptr;
            #pragma unroll
            for (int i = 0; i < 4; ++i) {
                int idx = t + i*256;           // 0..1023, 8 chunks per row
                int row = idx >> 3, c8 = idx & 7;
                short8 v = *(const short8*)(Ab + (size_t)(m0+row)*D_MODEL + k0 + c8*8);
                int byte = (row*128 + c8*16) ^ ((row & 7) << 4);
                *(short8*)((char*)Alds + byte) = v;
            }
        }
        #pragma unroll
        for (int i = 0; i < 4; ++i) {
            int idx = t + i*256;
            int row = idx >> 3, c8 = idx & 7;
            short8 v = *(const short8*)(Bt + (size_t)(n0+row)*D_MODEL + k0 + c8*8);
            int byte = (row*128 + c8*16) ^ ((row & 7) << 4);
            *(short8*)((char*)Blds + byte) = v;
        }
        __syncthreads();

        #pragma unroll
        for (int kk = 0; kk < 2; ++kk) {
            short8 af[4], bfr[4];
            #pragma unroll
            for (int mi = 0; mi < 4; ++mi) {
                int row = wm*64 + mi*16 + l15;
                int byte = (row*128 + kk*64 + lg*16) ^ ((row & 7) << 4);
                af[mi] = *(const short8*)((const char*)Alds + byte);
            }
            #pragma unroll
            for (int ni = 0; ni < 4; ++ni) {
                int row = wn*64 + ni*16 + l15;
                int byte = (row*128 + kk*64 + lg*16) ^ ((row & 7) << 4);
                bfr[ni] = *(const short8*)((const char*)Blds + byte);
            }
            #pragma unroll
            for (int mi = 0; mi < 4; ++mi)
                #pragma unroll
                for (int ni = 0; ni < 4; ++ni)
                    acc[mi][ni] = __builtin_amdgcn_mfma_f32_16x16x32_bf16(
                        af[mi], bfr[ni], acc[mi][ni], 0, 0, 0);
        }
        __syncthreads();
    }

    // epilogue: C/D layout col = lane&15, row = (lane>>4)*4 + reg
    #pragma unroll
    for (int mi = 0; mi < 4; ++mi)
        #pragma unroll
        for (int ni = 0; ni < 4; ++ni) {
            int col = n0 + wn*64 + ni*16 + l15;
            float bv = bias[col];
            if (OUTMODE == 2) {
                // V^T: out[((b*16+h)*64 + d)*SEQ + s], 4 consecutive s packed
                int h = col >> 6, d = col & 63;
                int row0 = m0 + wm*64 + mi*16 + lg*4;
                int bb = row0 >> 11, s = row0 & 2047;
                unsigned long long pk = 0;
                #pragma unroll
                for (int r = 0; r < 4; ++r) {
                    float v = acc[mi][ni][r] + bv;
                    if (QSCALE) v *= 0.125f;
                    pk |= (unsigned long long)f2bf(v) << (16*r);
                }
                *(unsigned long long*)((unsigned short*)Out
                    + ((size_t)((bb*NHEADS + h)*64 + d))*SEQ + s) = pk;
            } else {
                #pragma unroll
                for (int r = 0; r < 4; ++r) {
                    int row = m0 + wm*64 + mi*16 + lg*4 + r;
                    float v = acc[mi][ni][r] + bv;
                    if (QSCALE) v *= 0.125f;
                    if (OUTMODE == 1) {
                        int bb = row >> 11, s = row & 2047;     // row = b*2048+s
                        int h = col >> 6, d = col & 63;         // col = h*64+d
                        ((unsigned short*)Out)[(((size_t)(bb*NHEADS + h)*SEQ + s) << 6) + d] = f2bf(v);
                    } else {
                        ((float*)Out)[(size_t)row*D_MODEL + col] = v;
                    }
                }
            }
        }
}

// ---------- flash attention, swapped QK^T, lane-parallel softmax ----------
// block = 256 thr (4 waves), 64 q rows per block (16/wave), KVBLK=64.
// qh,kh: [b,h,s,64] bf16 (Q pre-scaled by 0.125).  vt: [b,h,64,s] bf16.
__global__ __launch_bounds__(256) void attn_kernel(const unsigned short* __restrict__ qh,
                                                   const unsigned short* __restrict__ kh,
                                                   const unsigned short* __restrict__ vt,
                                                   unsigned short* __restrict__ xout) {
    __shared__ __attribute__((aligned(16))) unsigned short Klds[64*64];   // [kv][d] swz
    __shared__ __attribute__((aligned(16))) unsigned short Vtl[64*64];    // [d][kv] swz
    __shared__ __attribute__((aligned(16))) unsigned short Plds[4*1024];  // per-wave [q][kv] swz

    const int qb = blockIdx.x;     // 0..31
    const int bh = blockIdx.y;     // 0..63
    const int t = threadIdx.x;
    const int lane = t & 63;
    const int w = t >> 6;
    const int l15 = lane & 15, lg = lane >> 4;

    const unsigned short* qbase = qh + (size_t)bh * SEQ * 64;
    const unsigned short* kbase = kh + (size_t)bh * SEQ * 64;
    const unsigned short* vtbase = vt + (size_t)bh * 64 * SEQ;
    unsigned short* pw = Plds + w * 1024;   // 16 rows x 64 kv, stride 128B

    // Q fragments hoisted: wave w owns q rows qb*64+w*16 .. +15 (lane's row = +l15)
    const int qrow = qb*64 + w*16 + l15;
    short8 qf0 = *(const short8*)(qbase + (size_t)qrow*64 + lg*8);
    short8 qf1 = *(const short8*)(qbase + (size_t)qrow*64 + 32 + lg*8);

    float m = -1e30f, lsum = 0.f;
    f32x4 o[4];                    // o[nb][r]: q = lg*4+r, d = nb*16+l15
    #pragma unroll
    for (int nb = 0; nb < 4; ++nb) o[nb] = (f32x4)(0.0f);

    for (int kv0 = 0; kv0 < SEQ; kv0 += 64) {
        // stage K[kv][d] and Vt[d][kv], both 64x64 bf16, same swizzle
        #pragma unroll
        for (int i = 0; i < 2; ++i) {
            int idx = t + i*256;
            int row = idx >> 3, c8 = idx & 7;
            int byte = (row*128 + c8*16) ^ ((row & 7) << 4);
            short8 kvv = *(const short8*)(kbase + (size_t)(kv0+row)*64 + c8*8);
            *(short8*)((char*)Klds + byte) = kvv;
            short8 vv = *(const short8*)(vtbase + (size_t)row*SEQ + kv0 + c8*8);
            *(short8*)((char*)Vtl + byte) = vv;
        }
        __syncthreads();

        // S^T = K Q^T : D row = kv (lg*4+r +16*nb), col = q (l15)
        f32x4 s4[4];
        #pragma unroll
        for (int nb = 0; nb < 4; ++nb) {
            int krow = nb*16 + l15;
            int b0 = (krow*128 + lg*16) ^ ((krow & 7) << 4);
            int b1 = (krow*128 + 64 + lg*16) ^ ((krow & 7) << 4);
            short8 kf0 = *(const short8*)((const char*)Klds + b0);
            short8 kf1 = *(const short8*)((const char*)Klds + b1);
            f32x4 s = (f32x4)(0.0f);
            s = __builtin_amdgcn_mfma_f32_16x16x32_bf16(kf0, qf0, s, 0, 0, 0);
            s = __builtin_amdgcn_mfma_f32_16x16x32_bf16(kf1, qf1, s, 0, 0, 0);
            s4[nb] = s;
        }

        // lane-parallel online softmax: this lane owns q row (qb*64+w*16+l15),
        // holding kv = nb*16 + lg*4 + r; reduce across lg with 2 shfls.
        float tm = -1e30f;
        #pragma unroll
        for (int nb = 0; nb < 4; ++nb)
            tm = fmaxf(tm, fmaxf(fmaxf(s4[nb][0], s4[nb][1]), fmaxf(s4[nb][2], s4[nb][3])));
        tm = fmaxf(tm, __shfl_xor(tm, 16));
        tm = fmaxf(tm, __shfl_xor(tm, 32));

        if (__any(tm > m + 8.0f)) {          // defer-max: rescale only on growth
            float mnew = fmaxf(m, tm);
            float alpha = __expf(m - mnew);  // first tile: exp(-huge)=0
            lsum *= alpha;
            m = mnew;
            #pragma unroll
            for (int r = 0; r < 4; ++r) {
                float ar = __shfl(alpha, lg*4 + r);
                #pragma unroll
                for (int nb = 0; nb < 4; ++nb) o[nb][r] *= ar;
            }
        }

        float ts = 0.f;
        float p[16];
        #pragma unroll
        for (int nb = 0; nb < 4; ++nb)
            #pragma unroll
            for (int r = 0; r < 4; ++r) {
                float pv = __expf(s4[nb][r] - m);
                p[nb*4 + r] = pv;
                ts += pv;
            }
        ts += __shfl_xor(ts, 16);
        ts += __shfl_xor(ts, 32);
        lsum += ts;

        // write P[q=l15][kv] as packed u32, swizzled stride-128B rows
        #pragma unroll
        for (int nb = 0; nb < 4; ++nb)
            #pragma unroll
            for (int r2 = 0; r2 < 2; ++r2) {
                unsigned int pk = (unsigned int)f2bf(p[nb*4 + 2*r2])
                                | ((unsigned int)f2bf(p[nb*4 + 2*r2 + 1]) << 16);
                int byte = (l15*128 + nb*32 + lg*8 + r2*4) ^ ((l15 & 7) << 4);
                *(unsigned int*)((char*)pw + byte) = pk;
            }

        // O += P V : A = P rows (q=l15, kv contig), B = Vt rows (d=l15)
        #pragma unroll
        for (int kk = 0; kk < 2; ++kk) {
            int pb = (l15*128 + kk*64 + lg*16) ^ ((l15 & 7) << 4);
            short8 pa = *(const short8*)((const char*)pw + pb);
            #pragma unroll
            for (int nb = 0; nb < 4; ++nb) {
                int vrow = nb*16 + l15;
                int byte = (vrow*128 + kk*64 + lg*16) ^ ((vrow & 7) << 4);
                short8 vf = *(const short8*)((const char*)Vtl + byte);
                o[nb] = __builtin_amdgcn_mfma_f32_16x16x32_bf16(pa, vf, o[nb], 0, 0, 0);
            }
        }
        __syncthreads();
    }

    // epilogue: x[b][s][h*64+d] bf16; lsum lives at lane l15=q, broadcast
    float lr[4];
    #pragma unroll
    for (int r = 0; r < 4; ++r) lr[r] = __shfl(lsum, lg*4 + r);
    const int bb = bh >> 4, h = bh & 15;
    #pragma unroll
    for (int nb = 0; nb < 4; ++nb)
        #pragma unroll
        for (int r = 0; r < 4; ++r) {
            int s = qb*64 + w*16 + lg*4 + r;
            int d = nb*16 + l15;
            xout[((size_t)(bb*SEQ + s))*D_MODEL + h*64 + d] = f2bf(o[nb][r] / lr[r]);
        }
}

extern "C" void kernel_launch(void* const* d_in, const int* in_sizes, int n_in,
                              void* d_out, int out_size, void* d_ws, size_t ws_size,
                              hipStream_t stream) {
    (void)in_sizes; (void)n_in; (void)out_size; (void)ws_size;
    const float* q  = (const float*)d_in[0];
    const float* k  = (const float*)d_in[1];
    const float* v  = (const float*)d_in[2];
    const float* wq = (const float*)d_in[3];
    const float* bq = (const float*)d_in[4];
    const float* wk = (const float*)d_in[5];
    const float* bk = (const float*)d_in[6];
    const float* wv = (const float*)d_in[7];
    const float* bv = (const float*)d_in[8];
    const float* wo = (const float*)d_in[9];
    const float* bo = (const float*)d_in[10];

    // workspace layout (72 MB total)
    char* ws = (char*)d_ws;
    unsigned short* wqt = (unsigned short*)(ws);                    // 2 MB each
    unsigned short* wkt = (unsigned short*)(ws + (2ull << 20));
    unsigned short* wvt = (unsigned short*)(ws + (4ull << 20));
    unsigned short* wot = (unsigned short*)(ws + (6ull << 20));
    unsigned short* qhd = (unsigned short*)(ws + (8ull << 20));     // 16 MB each
    unsigned short* khd = (unsigned short*)(ws + (24ull << 20));
    unsigned short* vtd = (unsigned short*)(ws + (40ull << 20));
    unsigned short* xat = (unsigned short*)(ws + (56ull << 20));

    dim3 tgrid(D_MODEL/32, D_MODEL/32);
    hipLaunchKernelGGL(wtrans_kernel, tgrid, dim3(256), 0, stream, wq, wqt);
    hipLaunchKernelGGL(wtrans_kernel, tgrid, dim3(256), 0, stream, wk, wkt);
    hipLaunchKernelGGL(wtrans_kernel, tgrid, dim3(256), 0, stream, wv, wvt);
    hipLaunchKernelGGL(wtrans_kernel, tgrid, dim3(256), 0, stream, wo, wot);

    dim3 ggrid(ROWS/128, D_MODEL/128);
    hipLaunchKernelGGL((gemm_kernel<1,1,1>), ggrid, dim3(256), 0, stream,
                       (const void*)q, wqt, bq, (void*)qhd);   // Q, scaled 0.125
    hipLaunchKernelGGL((gemm_kernel<1,1,0>), ggrid, dim3(256), 0, stream,
                       (const void*)k, wkt, bk, (void*)khd);   // K
    hipLaunchKernelGGL((gemm_kernel<1,2,0>), ggrid, dim3(256), 0, stream,
                       (const void*)v, wvt, bv, (void*)vtd);   // V -> V^T layout

    hipLaunchKernelGGL(attn_kernel, dim3(SEQ/64, BATCH*NHEADS), dim3(256), 0, stream,
                       qhd, khd, vtd, xat);

    hipLaunchKernelGGL((gemm_kernel<0,0,0>), ggrid, dim3(256), 0, stream,
                       (const void*)xat, wot, bo, d_out);
}

// Round 3
// 259.854 us; speedup vs baseline: 1.3606x; 1.1464x over previous
//
#include <hip/hip_runtime.h>
#include <hip/hip_bf16.h>
#include <stdint.h>

#define D_MODEL 1024
#define SEQ 2048
#define BATCH 4
#define NHEADS 16
#define ROWS (BATCH*SEQ)   // 8192

// Q pre-scale: (1/sqrt(64)) * log2(e) so attention softmax can use v_exp_f32 (2^x)
#define QKSCALE 0.18033688011f
#define DEFER_THR 11.5f    // 8 * log2(e)

typedef __attribute__((ext_vector_type(4))) float f32x4;
typedef __attribute__((ext_vector_type(8))) short short8;

#if __has_builtin(__builtin_amdgcn_exp2f)
#define EXP2(x) __builtin_amdgcn_exp2f(x)
#else
#define EXP2(x) exp2f(x)
#endif

__device__ __forceinline__ unsigned short f2bf(float f) {
    unsigned int x = __builtin_bit_cast(unsigned int, f);
    x += 0x7fffu + ((x >> 16) & 1u);   // RNE
    return (unsigned short)(x >> 16);
}

// v_cvt_pk_bf16_f32: lo = bf16(a), hi = bf16(b)  (RNE)
__device__ __forceinline__ unsigned int cvtpk(float a, float b) {
    unsigned int r;
    asm("v_cvt_pk_bf16_f32 %0, %1, %2" : "=v"(r) : "v"(a), "v"(b));
    return r;
}

// ---------- weight transpose + f32->bf16: wt[n][k] = bf16(w[k][n]) ----------
__global__ __launch_bounds__(256) void wtrans_kernel(const float* __restrict__ w,
                                                     unsigned short* __restrict__ wt) {
    __shared__ float tile[32][33];
    int tx = threadIdx.x & 31;
    int ty = threadIdx.x >> 5;           // 0..7
    int r0 = blockIdx.y * 32, c0 = blockIdx.x * 32;
    #pragma unroll
    for (int i = 0; i < 4; ++i)
        tile[ty + 8*i][tx] = w[(size_t)(r0 + ty + 8*i) * D_MODEL + (c0 + tx)];
    __syncthreads();
    #pragma unroll
    for (int i = 0; i < 4; ++i)
        wt[(size_t)(c0 + ty + 8*i) * D_MODEL + (r0 + tx)] = f2bf(tile[tx][ty + 8*i]);
}

// ---------- GEMM: C[8192x1024] = A[8192x1024] * Bt^T (+bias) ----------
// Bt is [N][K] bf16.  AF32: A is f32 (convert while staging).
// OUTMODE 0: f32 row-major.  1: bf16 head layout [b,h,s,64].
//         2: bf16 TRANSPOSED head layout [b,h,64,s] (for V).
// QSCALE: multiply output by QKSCALE (fold 1/sqrt(d_k)*log2e into Q projection).
template<int AF32, int OUTMODE, int QSCALE>
__global__ __launch_bounds__(256) void gemm_kernel(const void* __restrict__ Aptr,
                                                   const unsigned short* __restrict__ Bt,
                                                   const float* __restrict__ bias,
                                                   void* __restrict__ Out) {
    __shared__ __attribute__((aligned(16))) unsigned short Alds[128*64];
    __shared__ __attribute__((aligned(16))) unsigned short Blds[128*64];
    const int m0 = blockIdx.x * 128;
    const int n0 = blockIdx.y * 128;
    const int t = threadIdx.x;
    const int lane = t & 63;
    const int w = t >> 6;
    const int wm = w >> 1, wn = w & 1;        // 2x2 wave grid, 64x64 each
    const int l15 = lane & 15, lg = lane >> 4;

    f32x4 acc[4][4];
    #pragma unroll
    for (int i = 0; i < 4; ++i)
        #pragma unroll
        for (int j = 0; j < 4; ++j) acc[i][j] = (f32x4)(0.0f);

    for (int k0 = 0; k0 < D_MODEL; k0 += 64) {
        if (AF32) {
            const float* Af = (const float*)Aptr;
            #pragma unroll
            for (int i = 0; i < 8; ++i) {
                int idx = t + i*256;           // 0..2047, 16 float4 per row
                int row = idx >> 4, c4 = idx & 15;
                f32x4 v = *(const f32x4*)(Af + (size_t)(m0+row)*D_MODEL + k0 + c4*4);
                unsigned int lo = cvtpk(v[0], v[1]);
                unsigned int hi = cvtpk(v[2], v[3]);
                unsigned long long pk = (unsigned long long)lo
                                      | ((unsigned long long)hi << 32);
                int byte = (row*128 + c4*8) ^ ((row & 7) << 4);
                *(unsigned long long*)((char*)Alds + byte) = pk;
            }
        } else {
            const unsigned short* Ab = (const unsigned short*)Aptr;
            #pragma unroll
            for (int i = 0; i < 4; ++i) {
                int idx = t + i*256;           // 0..1023, 8 chunks per row
                int row = idx >> 3, c8 = idx & 7;
                short8 v = *(const short8*)(Ab + (size_t)(m0+row)*D_MODEL + k0 + c8*8);
                int byte = (row*128 + c8*16) ^ ((row & 7) << 4);
                *(short8*)((char*)Alds + byte) = v;
            }
        }
        #pragma unroll
        for (int i = 0; i < 4; ++i) {
            int idx = t + i*256;
            int row = idx >> 3, c8 = idx & 7;
            short8 v = *(const short8*)(Bt + (size_t)(n0+row)*D_MODEL + k0 + c8*8);
            int byte = (row*128 + c8*16) ^ ((row & 7) << 4);
            *(short8*)((char*)Blds + byte) = v;
        }
        __syncthreads();

        #pragma unroll
        for (int kk = 0; kk < 2; ++kk) {
            short8 af[4], bfr[4];
            #pragma unroll
            for (int mi = 0; mi < 4; ++mi) {
                int row = wm*64 + mi*16 + l15;
                int byte = (row*128 + kk*64 + lg*16) ^ ((row & 7) << 4);
                af[mi] = *(const short8*)((const char*)Alds + byte);
            }
            #pragma unroll
            for (int ni = 0; ni < 4; ++ni) {
                int row = wn*64 + ni*16 + l15;
                int byte = (row*128 + kk*64 + lg*16) ^ ((row & 7) << 4);
                bfr[ni] = *(const short8*)((const char*)Blds + byte);
            }
            #pragma unroll
            for (int mi = 0; mi < 4; ++mi)
                #pragma unroll
                for (int ni = 0; ni < 4; ++ni)
                    acc[mi][ni] = __builtin_amdgcn_mfma_f32_16x16x32_bf16(
                        af[mi], bfr[ni], acc[mi][ni], 0, 0, 0);
        }
        __syncthreads();
    }

    // epilogue: C/D layout col = lane&15, row = (lane>>4)*4 + reg
    #pragma unroll
    for (int mi = 0; mi < 4; ++mi)
        #pragma unroll
        for (int ni = 0; ni < 4; ++ni) {
            int col = n0 + wn*64 + ni*16 + l15;
            float bv = bias[col];
            if (OUTMODE == 2) {
                // V^T: out[((b*16+h)*64 + d)*SEQ + s], 4 consecutive s packed
                int h = col >> 6, d = col & 63;
                int row0 = m0 + wm*64 + mi*16 + lg*4;
                int bb = row0 >> 11, s = row0 & 2047;
                unsigned long long pk = 0;
                #pragma unroll
                for (int r = 0; r < 4; ++r) {
                    float v = acc[mi][ni][r] + bv;
                    pk |= (unsigned long long)f2bf(v) << (16*r);
                }
                *(unsigned long long*)((unsigned short*)Out
                    + ((size_t)((bb*NHEADS + h)*64 + d))*SEQ + s) = pk;
            } else {
                #pragma unroll
                for (int r = 0; r < 4; ++r) {
                    int row = m0 + wm*64 + mi*16 + lg*4 + r;
                    float v = acc[mi][ni][r] + bv;
                    if (QSCALE) v *= QKSCALE;
                    if (OUTMODE == 1) {
                        int bb = row >> 11, s = row & 2047;     // row = b*2048+s
                        int h = col >> 6, d = col & 63;         // col = h*64+d
                        ((unsigned short*)Out)[(((size_t)(bb*NHEADS + h)*SEQ + s) << 6) + d] = f2bf(v);
                    } else {
                        ((float*)Out)[(size_t)row*D_MODEL + col] = v;
                    }
                }
            }
        }
}

// ---------- flash attention: swapped QK^T, in-register P via permuted-K LDS ----
// K row kv stored at phys row sigma(kv) (swap lg<->h bit fields).  Reading A-frag
// rows nb*16+l15 then yields score D-values at kv = (nb>>1)*32 + lg*8 + (nb&1)*4+r
// which is exactly the PV A-fragment's lane-local layout -> P never leaves regs.
__global__ __launch_bounds__(256) void attn_kernel(const unsigned short* __restrict__ qh,
                                                   const unsigned short* __restrict__ kh,
                                                   const unsigned short* __restrict__ vt,
                                                   unsigned short* __restrict__ xout) {
    __shared__ __attribute__((aligned(16))) unsigned short Klds[2][64*64];
    __shared__ __attribute__((aligned(16))) unsigned short Vtl[2][64*64];

    const int qb = blockIdx.x;     // 0..31
    const int bh = blockIdx.y;     // 0..63
    const int t = threadIdx.x;
    const int lane = t & 63;
    const int w = t >> 6;
    const int l15 = lane & 15, lg = lane >> 4;

    const unsigned short* qbase = qh + (size_t)bh * SEQ * 64;
    const unsigned short* kbase = kh + (size_t)bh * SEQ * 64;
    const unsigned short* vtbase = vt + (size_t)bh * 64 * SEQ;

    // Q fragments hoisted (Q pre-scaled by QKSCALE in projection)
    const int qrow = qb*64 + w*16 + l15;
    short8 qf0 = *(const short8*)(qbase + (size_t)qrow*64 + lg*8);
    short8 qf1 = *(const short8*)(qbase + (size_t)qrow*64 + 32 + lg*8);

    // staging geometry (loop-invariant)
    const int c8 = t & 7;
    const int r0 = t >> 3;               // 0..31
    const int r1 = r0 + 32;
    // sigma(kv): kv = {b5=kk, b4b3=lg, b2=h, b1b0=r} -> phys = {kk, h, lg, r}
    const int p0 = (r0 & 0x23) | ((r0 & 4) << 2) | ((r0 & 0x18) >> 1);
    const int p1 = (r1 & 0x23) | ((r1 & 4) << 2) | ((r1 & 0x18) >> 1);
    const int kb0 = (p0*128 + c8*16) ^ ((p0 & 7) << 4);
    const int kb1 = (p1*128 + c8*16) ^ ((p1 & 7) << 4);
    const int vb0 = (r0*128 + c8*16) ^ ((r0 & 7) << 4);
    const int vb1 = (r1*128 + c8*16) ^ ((r1 & 7) << 4);
    const unsigned short* kg0 = kbase + r0*64 + c8*8;
    const unsigned short* kg1 = kbase + r1*64 + c8*8;
    const unsigned short* vg0 = vtbase + (size_t)r0*SEQ + c8*8;
    const unsigned short* vg1 = vtbase + (size_t)r1*SEQ + c8*8;

    // hoisted fragment read offsets (same formula for K and Vt)
    int fb[4][2];
    #pragma unroll
    for (int nb = 0; nb < 4; ++nb) {
        int rr = nb*16 + l15;
        int sw = (rr & 7) << 4;
        fb[nb][0] = (rr*128 + lg*16) ^ sw;
        fb[nb][1] = (rr*128 + 64 + lg*16) ^ sw;
    }

    float m = -1e30f, lsum = 0.f;
    f32x4 o[4];                    // o[nb][r]: q = lg*4+r, d = nb*16+l15
    #pragma unroll
    for (int nb = 0; nb < 4; ++nb) o[nb] = (f32x4)(0.0f);

    // prologue: stage tile 0 into buffer 0
    short8 kr0 = *(const short8*)(kg0);
    short8 kr1 = *(const short8*)(kg1);
    short8 vr0 = *(const short8*)(vg0);
    short8 vr1 = *(const short8*)(vg1);
    *(short8*)((char*)Klds[0] + kb0) = kr0;
    *(short8*)((char*)Klds[0] + kb1) = kr1;
    *(short8*)((char*)Vtl[0] + vb0) = vr0;
    *(short8*)((char*)Vtl[0] + vb1) = vr1;
    __syncthreads();

    const int NT = SEQ/64;
    int c = 0;
    for (int ti = 0; ti < NT; ++ti) {
        // issue next-tile global loads early (latency hides under compute)
        if (ti + 1 < NT) {
            int off = (ti + 1) * 64;
            kr0 = *(const short8*)(kg0 + (size_t)off*64);
            kr1 = *(const short8*)(kg1 + (size_t)off*64);
            vr0 = *(const short8*)(vg0 + off);
            vr1 = *(const short8*)(vg1 + off);
        }
        const char* Kc = (const char*)Klds[c];
        const char* Vc = (const char*)Vtl[c];

        // S^T = K Q^T
        f32x4 s4[4];
        #pragma unroll
        for (int nb = 0; nb < 4; ++nb) {
            short8 kf0 = *(const short8*)(Kc + fb[nb][0]);
            short8 kf1 = *(const short8*)(Kc + fb[nb][1]);
            f32x4 s = (f32x4)(0.0f);
            s = __builtin_amdgcn_mfma_f32_16x16x32_bf16(kf0, qf0, s, 0, 0, 0);
            s = __builtin_amdgcn_mfma_f32_16x16x32_bf16(kf1, qf1, s, 0, 0, 0);
            s4[nb] = s;
        }

        // lane-parallel online softmax (log2 units); lane owns q = l15
        float tm = s4[0][0];
        #pragma unroll
        for (int nb = 0; nb < 4; ++nb)
            #pragma unroll
            for (int r = 0; r < 4; ++r) tm = fmaxf(tm, s4[nb][r]);
        tm = fmaxf(tm, __shfl_xor(tm, 16));
        tm = fmaxf(tm, __shfl_xor(tm, 32));

        if (__any(tm > m + DEFER_THR)) {     // defer-max (T13)
            float mnew = fmaxf(m, tm);
            float alpha = EXP2(m - mnew);    // first tile: 2^-huge = 0
            lsum *= alpha;
            m = mnew;
            #pragma unroll
            for (int r = 0; r < 4; ++r) {
                float ar = __shfl(alpha, lg*4 + r);
                #pragma unroll
                for (int nb = 0; nb < 4; ++nb) o[nb][r] *= ar;
            }
        }

        float p[16];
        float ts = 0.f;
        #pragma unroll
        for (int nb = 0; nb < 4; ++nb)
            #pragma unroll
            for (int r = 0; r < 4; ++r) {
                float pv = EXP2(s4[nb][r] - m);
                p[nb*4 + r] = pv;
                ts += pv;
            }
        ts += __shfl_xor(ts, 16);
        ts += __shfl_xor(ts, 32);
        lsum += ts;

        // pack PA fragments fully in-register: pa[kk] covers kv = kk*32+lg*8..+7
        union U { short8 s; unsigned int u[4]; } pa0, pa1;
        pa0.u[0] = cvtpk(p[0],  p[1]);  pa0.u[1] = cvtpk(p[2],  p[3]);
        pa0.u[2] = cvtpk(p[4],  p[5]);  pa0.u[3] = cvtpk(p[6],  p[7]);
        pa1.u[0] = cvtpk(p[8],  p[9]);  pa1.u[1] = cvtpk(p[10], p[11]);
        pa1.u[2] = cvtpk(p[12], p[13]); pa1.u[3] = cvtpk(p[14], p[15]);

        // O += P V
        #pragma unroll
        for (int nb = 0; nb < 4; ++nb) {
            short8 vf = *(const short8*)(Vc + fb[nb][0]);
            o[nb] = __builtin_amdgcn_mfma_f32_16x16x32_bf16(pa0.s, vf, o[nb], 0, 0, 0);
        }
        #pragma unroll
        for (int nb = 0; nb < 4; ++nb) {
            short8 vf = *(const short8*)(Vc + fb[nb][1]);
            o[nb] = __builtin_amdgcn_mfma_f32_16x16x32_bf16(pa1.s, vf, o[nb], 0, 0, 0);
        }

        // write next tile into the other buffer
        if (ti + 1 < NT) {
            *(short8*)((char*)Klds[c^1] + kb0) = kr0;
            *(short8*)((char*)Klds[c^1] + kb1) = kr1;
            *(short8*)((char*)Vtl[c^1] + vb0) = vr0;
            *(short8*)((char*)Vtl[c^1] + vb1) = vr1;
        }
        __syncthreads();
        c ^= 1;
    }

    // epilogue: x[b][s][h*64+d] bf16
    float rl[4];
    #pragma unroll
    for (int r = 0; r < 4; ++r) rl[r] = 1.0f / __shfl(lsum, lg*4 + r);
    const int bb = bh >> 4, h = bh & 15;
    #pragma unroll
    for (int nb = 0; nb < 4; ++nb)
        #pragma unroll
        for (int r = 0; r < 4; ++r) {
            int s = qb*64 + w*16 + lg*4 + r;
            int d = nb*16 + l15;
            xout[((size_t)(bb*SEQ + s))*D_MODEL + h*64 + d] = f2bf(o[nb][r] * rl[r]);
        }
}

extern "C" void kernel_launch(void* const* d_in, const int* in_sizes, int n_in,
                              void* d_out, int out_size, void* d_ws, size_t ws_size,
                              hipStream_t stream) {
    (void)in_sizes; (void)n_in; (void)out_size; (void)ws_size;
    const float* q  = (const float*)d_in[0];
    const float* k  = (const float*)d_in[1];
    const float* v  = (const float*)d_in[2];
    const float* wq = (const float*)d_in[3];
    const float* bq = (const float*)d_in[4];
    const float* wk = (const float*)d_in[5];
    const float* bk = (const float*)d_in[6];
    const float* wv = (const float*)d_in[7];
    const float* bv = (const float*)d_in[8];
    const float* wo = (const float*)d_in[9];
    const float* bo = (const float*)d_in[10];

    // workspace layout (72 MB total)
    char* ws = (char*)d_ws;
    unsigned short* wqt = (unsigned short*)(ws);                    // 2 MB each
    unsigned short* wkt = (unsigned short*)(ws + (2ull << 20));
    unsigned short* wvt = (unsigned short*)(ws + (4ull << 20));
    unsigned short* wot = (unsigned short*)(ws + (6ull << 20));
    unsigned short* qhd = (unsigned short*)(ws + (8ull << 20));     // 16 MB each
    unsigned short* khd = (unsigned short*)(ws + (24ull << 20));
    unsigned short* vtd = (unsigned short*)(ws + (40ull << 20));
    unsigned short* xat = (unsigned short*)(ws + (56ull << 20));

    dim3 tgrid(D_MODEL/32, D_MODEL/32);
    hipLaunchKernelGGL(wtrans_kernel, tgrid, dim3(256), 0, stream, wq, wqt);
    hipLaunchKernelGGL(wtrans_kernel, tgrid, dim3(256), 0, stream, wk, wkt);
    hipLaunchKernelGGL(wtrans_kernel, tgrid, dim3(256), 0, stream, wv, wvt);
    hipLaunchKernelGGL(wtrans_kernel, tgrid, dim3(256), 0, stream, wo, wot);

    dim3 ggrid(ROWS/128, D_MODEL/128);
    hipLaunchKernelGGL((gemm_kernel<1,1,1>), ggrid, dim3(256), 0, stream,
                       (const void*)q, wqt, bq, (void*)qhd);   // Q, scaled
    hipLaunchKernelGGL((gemm_kernel<1,1,0>), ggrid, dim3(256), 0, stream,
                       (const void*)k, wkt, bk, (void*)khd);   // K
    hipLaunchKernelGGL((gemm_kernel<1,2,0>), ggrid, dim3(256), 0, stream,
                       (const void*)v, wvt, bv, (void*)vtd);   // V -> V^T layout

    hipLaunchKernelGGL(attn_kernel, dim3(SEQ/64, BATCH*NHEADS), dim3(256), 0, stream,
                       qhd, khd, vtd, xat);

    hipLaunchKernelGGL((gemm_kernel<0,0,0>), ggrid, dim3(256), 0, stream,
                       (const void*)xat, wot, bo, d_out);
}

// Round 4
// 228.268 us; speedup vs baseline: 1.5489x; 1.1384x over previous
//
#include <hip/hip_runtime.h>
#include <hip/hip_bf16.h>
#include <stdint.h>

#define D_MODEL 1024
#define SEQ 2048
#define BATCH 4
#define NHEADS 16
#define ROWS (BATCH*SEQ)   // 8192

// Q pre-scale: (1/sqrt(64)) * log2(e) so attention softmax can use v_exp_f32 (2^x)
#define QKSCALE 0.18033688011f
#define DEFER_THR 11.5f    // 8 * log2(e)

typedef __attribute__((ext_vector_type(4))) float f32x4;
typedef __attribute__((ext_vector_type(8))) short short8;

#if __has_builtin(__builtin_amdgcn_exp2f)
#define EXP2(x) __builtin_amdgcn_exp2f(x)
#else
#define EXP2(x) exp2f(x)
#endif

__device__ __forceinline__ unsigned short f2bf(float f) {
    unsigned int x = __builtin_bit_cast(unsigned int, f);
    x += 0x7fffu + ((x >> 16) & 1u);   // RNE
    return (unsigned short)(x >> 16);
}

// v_cvt_pk_bf16_f32: lo = bf16(a), hi = bf16(b)  (RNE)
__device__ __forceinline__ unsigned int cvtpk(float a, float b) {
    unsigned int r;
    asm("v_cvt_pk_bf16_f32 %0, %1, %2" : "=v"(r) : "v"(a), "v"(b));
    return r;
}

// ---------- weight transpose + f32->bf16: wt[n][k] = bf16(w[k][n]) ----------
__global__ __launch_bounds__(256) void wtrans_kernel(const float* __restrict__ w,
                                                     unsigned short* __restrict__ wt) {
    __shared__ float tile[32][33];
    int tx = threadIdx.x & 31;
    int ty = threadIdx.x >> 5;           // 0..7
    int r0 = blockIdx.y * 32, c0 = blockIdx.x * 32;
    #pragma unroll
    for (int i = 0; i < 4; ++i)
        tile[ty + 8*i][tx] = w[(size_t)(r0 + ty + 8*i) * D_MODEL + (c0 + tx)];
    __syncthreads();
    #pragma unroll
    for (int i = 0; i < 4; ++i)
        wt[(size_t)(c0 + ty + 8*i) * D_MODEL + (r0 + tx)] = f2bf(tile[tx][ty + 8*i]);
}

// ---------- GEMM: C[8192x1024] = A[8192x1024] * Bt^T (+bias) ----------
// Bt is [N][K] bf16.  AF32: A is f32 (convert while staging).
// OUTMODE 0: f32 row-major.  1: bf16 head layout [b,h,s,64].
//         2: bf16 TRANSPOSED head layout [b,h,64,s] (for V).
// QSCALE: multiply output by QKSCALE (fold 1/sqrt(d_k)*log2e into Q projection).
template<int AF32, int OUTMODE, int QSCALE>
__global__ __launch_bounds__(256) void gemm_kernel(const void* __restrict__ Aptr,
                                                   const unsigned short* __restrict__ Bt,
                                                   const float* __restrict__ bias,
                                                   void* __restrict__ Out) {
    __shared__ __attribute__((aligned(16))) unsigned short Alds[128*64];
    __shared__ __attribute__((aligned(16))) unsigned short Blds[128*64];
    const int m0 = blockIdx.x * 128;
    const int n0 = blockIdx.y * 128;
    const int t = threadIdx.x;
    const int lane = t & 63;
    const int w = t >> 6;
    const int wm = w >> 1, wn = w & 1;        // 2x2 wave grid, 64x64 each
    const int l15 = lane & 15, lg = lane >> 4;

    f32x4 acc[4][4];
    #pragma unroll
    for (int i = 0; i < 4; ++i)
        #pragma unroll
        for (int j = 0; j < 4; ++j) acc[i][j] = (f32x4)(0.0f);

    for (int k0 = 0; k0 < D_MODEL; k0 += 64) {
        if (AF32) {
            const float* Af = (const float*)Aptr;
            #pragma unroll
            for (int i = 0; i < 8; ++i) {
                int idx = t + i*256;           // 0..2047, 16 float4 per row
                int row = idx >> 4, c4 = idx & 15;
                f32x4 v = *(const f32x4*)(Af + (size_t)(m0+row)*D_MODEL + k0 + c4*4);
                unsigned int lo = cvtpk(v[0], v[1]);
                unsigned int hi = cvtpk(v[2], v[3]);
                unsigned long long pk = (unsigned long long)lo
                                      | ((unsigned long long)hi << 32);
                int byte = (row*128 + c4*8) ^ ((row & 7) << 4);
                *(unsigned long long*)((char*)Alds + byte) = pk;
            }
        } else {
            const unsigned short* Ab = (const unsigned short*)Aptr;
            #pragma unroll
            for (int i = 0; i < 4; ++i) {
                int idx = t + i*256;           // 0..1023, 8 chunks per row
                int row = idx >> 3, c8 = idx & 7;
                short8 v = *(const short8*)(Ab + (size_t)(m0+row)*D_MODEL + k0 + c8*8);
                int byte = (row*128 + c8*16) ^ ((row & 7) << 4);
                *(short8*)((char*)Alds + byte) = v;
            }
        }
        #pragma unroll
        for (int i = 0; i < 4; ++i) {
            int idx = t + i*256;
            int row = idx >> 3, c8 = idx & 7;
            short8 v = *(const short8*)(Bt + (size_t)(n0+row)*D_MODEL + k0 + c8*8);
            int byte = (row*128 + c8*16) ^ ((row & 7) << 4);
            *(short8*)((char*)Blds + byte) = v;
        }
        __syncthreads();

        #pragma unroll
        for (int kk = 0; kk < 2; ++kk) {
            short8 af[4], bfr[4];
            #pragma unroll
            for (int mi = 0; mi < 4; ++mi) {
                int row = wm*64 + mi*16 + l15;
                int byte = (row*128 + kk*64 + lg*16) ^ ((row & 7) << 4);
                af[mi] = *(const short8*)((const char*)Alds + byte);
            }
            #pragma unroll
            for (int ni = 0; ni < 4; ++ni) {
                int row = wn*64 + ni*16 + l15;
                int byte = (row*128 + kk*64 + lg*16) ^ ((row & 7) << 4);
                bfr[ni] = *(const short8*)((const char*)Blds + byte);
            }
            #pragma unroll
            for (int mi = 0; mi < 4; ++mi)
                #pragma unroll
                for (int ni = 0; ni < 4; ++ni)
                    acc[mi][ni] = __builtin_amdgcn_mfma_f32_16x16x32_bf16(
                        af[mi], bfr[ni], acc[mi][ni], 0, 0, 0);
        }
        __syncthreads();
    }

    // epilogue: C/D layout col = lane&15, row = (lane>>4)*4 + reg
    #pragma unroll
    for (int mi = 0; mi < 4; ++mi)
        #pragma unroll
        for (int ni = 0; ni < 4; ++ni) {
            int col = n0 + wn*64 + ni*16 + l15;
            float bv = bias[col];
            if (OUTMODE == 2) {
                // V^T: out[((b*16+h)*64 + d)*SEQ + s], 4 consecutive s packed
                int h = col >> 6, d = col & 63;
                int row0 = m0 + wm*64 + mi*16 + lg*4;
                int bb = row0 >> 11, s = row0 & 2047;
                unsigned long long pk = 0;
                #pragma unroll
                for (int r = 0; r < 4; ++r) {
                    float v = acc[mi][ni][r] + bv;
                    pk |= (unsigned long long)f2bf(v) << (16*r);
                }
                *(unsigned long long*)((unsigned short*)Out
                    + ((size_t)((bb*NHEADS + h)*64 + d))*SEQ + s) = pk;
            } else {
                #pragma unroll
                for (int r = 0; r < 4; ++r) {
                    int row = m0 + wm*64 + mi*16 + lg*4 + r;
                    float v = acc[mi][ni][r] + bv;
                    if (QSCALE) v *= QKSCALE;
                    if (OUTMODE == 1) {
                        int bb = row >> 11, s = row & 2047;     // row = b*2048+s
                        int h = col >> 6, d = col & 63;         // col = h*64+d
                        ((unsigned short*)Out)[(((size_t)(bb*NHEADS + h)*SEQ + s) << 6) + d] = f2bf(v);
                    } else {
                        ((float*)Out)[(size_t)row*D_MODEL + col] = v;
                    }
                }
            }
        }
}

// ---------- flash attention: swapped QK^T, in-register P via permuted-K LDS ----
// 8 waves x 16 q-rows = 128 q rows per block; KVBLK=64; double-buffered LDS.
// K row kv stored at phys row sigma(kv) (swap lg<->h bit fields) so the QK^T
// D-values land at the PV A-fragment's lane-local kv positions -> P stays in regs.
__global__ __launch_bounds__(512, 4) void attn_kernel(const unsigned short* __restrict__ qh,
                                                      const unsigned short* __restrict__ kh,
                                                      const unsigned short* __restrict__ vt,
                                                      unsigned short* __restrict__ xout) {
    __shared__ __attribute__((aligned(16))) unsigned short Klds[2][64*64];
    __shared__ __attribute__((aligned(16))) unsigned short Vtl[2][64*64];

    const int qb = blockIdx.x;     // 0..15 (128 q rows each)
    const int bh = blockIdx.y;     // 0..63
    const int t = threadIdx.x;     // 0..511
    const int lane = t & 63;
    const int w = t >> 6;          // 0..7
    const int l15 = lane & 15, lg = lane >> 4;

    const unsigned short* qbase = qh + (size_t)bh * SEQ * 64;
    const unsigned short* kbase = kh + (size_t)bh * SEQ * 64;
    const unsigned short* vtbase = vt + (size_t)bh * 64 * SEQ;

    // Q fragments hoisted (Q pre-scaled by QKSCALE in projection)
    const int qrow = qb*128 + w*16 + l15;
    short8 qf0 = *(const short8*)(qbase + (size_t)qrow*64 + lg*8);
    short8 qf1 = *(const short8*)(qbase + (size_t)qrow*64 + 32 + lg*8);

    // staging geometry: 512 threads, one 16B chunk per matrix each
    const int c8 = t & 7;
    const int r0 = t >> 3;               // 0..63
    // sigma(kv): kv = {b5=kk, b4b3=lg, b2=h, b1b0=r} -> phys = {kk, h, lg, r}
    const int p0 = (r0 & 0x23) | ((r0 & 4) << 2) | ((r0 & 0x18) >> 1);
    const int kb0 = (p0*128 + c8*16) ^ ((p0 & 7) << 4);
    const int vb0 = (r0*128 + c8*16) ^ ((r0 & 7) << 4);
    const unsigned short* kg0 = kbase + r0*64 + c8*8;
    const unsigned short* vg0 = vtbase + (size_t)r0*SEQ + c8*8;

    // hoisted fragment read offsets (same formula for K and Vt)
    int fb[4][2];
    #pragma unroll
    for (int nb = 0; nb < 4; ++nb) {
        int rr = nb*16 + l15;
        int sw = (rr & 7) << 4;
        fb[nb][0] = (rr*128 + lg*16) ^ sw;
        fb[nb][1] = (rr*128 + 64 + lg*16) ^ sw;
    }

    float m = -1e30f, lsum = 0.f;
    f32x4 o[4];                    // o[nb][r]: q = lg*4+r, d = nb*16+l15
    #pragma unroll
    for (int nb = 0; nb < 4; ++nb) o[nb] = (f32x4)(0.0f);

    // prologue: stage tile 0 into buffer 0
    short8 kr0 = *(const short8*)(kg0);
    short8 vr0 = *(const short8*)(vg0);
    *(short8*)((char*)Klds[0] + kb0) = kr0;
    *(short8*)((char*)Vtl[0] + vb0) = vr0;
    __syncthreads();

    const int NT = SEQ/64;
    #pragma unroll 2
    for (int ti = 0; ti < NT; ++ti) {
        const int c = ti & 1;
        // issue next-tile global loads early (latency hides under compute)
        if (ti + 1 < NT) {
            int off = (ti + 1) * 64;
            kr0 = *(const short8*)(kg0 + (size_t)off*64);
            vr0 = *(const short8*)(vg0 + off);
        }
        const char* Kc = (const char*)Klds[c];
        const char* Vc = (const char*)Vtl[c];

        // S^T = K Q^T
        f32x4 s4[4];
        #pragma unroll
        for (int nb = 0; nb < 4; ++nb) {
            short8 kf0 = *(const short8*)(Kc + fb[nb][0]);
            short8 kf1 = *(const short8*)(Kc + fb[nb][1]);
            f32x4 s = (f32x4)(0.0f);
            s = __builtin_amdgcn_mfma_f32_16x16x32_bf16(kf0, qf0, s, 0, 0, 0);
            s = __builtin_amdgcn_mfma_f32_16x16x32_bf16(kf1, qf1, s, 0, 0, 0);
            s4[nb] = s;
        }

        // lane-parallel online softmax (log2 units); lane owns q = l15
        float tm = s4[0][0];
        #pragma unroll
        for (int nb = 0; nb < 4; ++nb)
            #pragma unroll
            for (int r = 0; r < 4; ++r) tm = fmaxf(tm, s4[nb][r]);
        tm = fmaxf(tm, __shfl_xor(tm, 16));
        tm = fmaxf(tm, __shfl_xor(tm, 32));

        if (__any(tm > m + DEFER_THR)) {     // defer-max (T13)
            float mnew = fmaxf(m, tm);
            float alpha = EXP2(m - mnew);    // first tile: 2^-huge = 0
            lsum *= alpha;
            m = mnew;
            #pragma unroll
            for (int r = 0; r < 4; ++r) {
                float ar = __shfl(alpha, lg*4 + r);
                #pragma unroll
                for (int nb = 0; nb < 4; ++nb) o[nb][r] *= ar;
            }
        }

        float p[16];
        float ts = 0.f;
        #pragma unroll
        for (int nb = 0; nb < 4; ++nb)
            #pragma unroll
            for (int r = 0; r < 4; ++r) {
                float pv = EXP2(s4[nb][r] - m);
                p[nb*4 + r] = pv;
                ts += pv;
            }
        ts += __shfl_xor(ts, 16);
        ts += __shfl_xor(ts, 32);
        lsum += ts;

        // pack PA fragments fully in-register: pa[kk] covers kv = kk*32+lg*8..+7
        union U { short8 s; unsigned int u[4]; } pa0, pa1;
        pa0.u[0] = cvtpk(p[0],  p[1]);  pa0.u[1] = cvtpk(p[2],  p[3]);
        pa0.u[2] = cvtpk(p[4],  p[5]);  pa0.u[3] = cvtpk(p[6],  p[7]);
        pa1.u[0] = cvtpk(p[8],  p[9]);  pa1.u[1] = cvtpk(p[10], p[11]);
        pa1.u[2] = cvtpk(p[12], p[13]); pa1.u[3] = cvtpk(p[14], p[15]);

        // O += P V
        #pragma unroll
        for (int nb = 0; nb < 4; ++nb) {
            short8 vf = *(const short8*)(Vc + fb[nb][0]);
            o[nb] = __builtin_amdgcn_mfma_f32_16x16x32_bf16(pa0.s, vf, o[nb], 0, 0, 0);
        }
        #pragma unroll
        for (int nb = 0; nb < 4; ++nb) {
            short8 vf = *(const short8*)(Vc + fb[nb][1]);
            o[nb] = __builtin_amdgcn_mfma_f32_16x16x32_bf16(pa1.s, vf, o[nb], 0, 0, 0);
        }

        // write next tile into the other buffer
        if (ti + 1 < NT) {
            *(short8*)((char*)Klds[c^1] + kb0) = kr0;
            *(short8*)((char*)Vtl[c^1] + vb0) = vr0;
        }
        __syncthreads();
    }

    // epilogue: x[b][s][h*64+d] bf16
    float rl[4];
    #pragma unroll
    for (int r = 0; r < 4; ++r) rl[r] = 1.0f / __shfl(lsum, lg*4 + r);
    const int bb = bh >> 4, h = bh & 15;
    #pragma unroll
    for (int nb = 0; nb < 4; ++nb)
        #pragma unroll
        for (int r = 0; r < 4; ++r) {
            int s = qb*128 + w*16 + lg*4 + r;
            int d = nb*16 + l15;
            xout[((size_t)(bb*SEQ + s))*D_MODEL + h*64 + d] = f2bf(o[nb][r] * rl[r]);
        }
}

extern "C" void kernel_launch(void* const* d_in, const int* in_sizes, int n_in,
                              void* d_out, int out_size, void* d_ws, size_t ws_size,
                              hipStream_t stream) {
    (void)in_sizes; (void)n_in; (void)out_size; (void)ws_size;
    const float* q  = (const float*)d_in[0];
    const float* k  = (const float*)d_in[1];
    const float* v  = (const float*)d_in[2];
    const float* wq = (const float*)d_in[3];
    const float* bq = (const float*)d_in[4];
    const float* wk = (const float*)d_in[5];
    const float* bk = (const float*)d_in[6];
    const float* wv = (const float*)d_in[7];
    const float* bv = (const float*)d_in[8];
    const float* wo = (const float*)d_in[9];
    const float* bo = (const float*)d_in[10];

    // workspace layout (72 MB total)
    char* ws = (char*)d_ws;
    unsigned short* wqt = (unsigned short*)(ws);                    // 2 MB each
    unsigned short* wkt = (unsigned short*)(ws + (2ull << 20));
    unsigned short* wvt = (unsigned short*)(ws + (4ull << 20));
    unsigned short* wot = (unsigned short*)(ws + (6ull << 20));
    unsigned short* qhd = (unsigned short*)(ws + (8ull << 20));     // 16 MB each
    unsigned short* khd = (unsigned short*)(ws + (24ull << 20));
    unsigned short* vtd = (unsigned short*)(ws + (40ull << 20));
    unsigned short* xat = (unsigned short*)(ws + (56ull << 20));

    dim3 tgrid(D_MODEL/32, D_MODEL/32);
    hipLaunchKernelGGL(wtrans_kernel, tgrid, dim3(256), 0, stream, wq, wqt);
    hipLaunchKernelGGL(wtrans_kernel, tgrid, dim3(256), 0, stream, wk, wkt);
    hipLaunchKernelGGL(wtrans_kernel, tgrid, dim3(256), 0, stream, wv, wvt);
    hipLaunchKernelGGL(wtrans_kernel, tgrid, dim3(256), 0, stream, wo, wot);

    dim3 ggrid(ROWS/128, D_MODEL/128);
    hipLaunchKernelGGL((gemm_kernel<1,1,1>), ggrid, dim3(256), 0, stream,
                       (const void*)q, wqt, bq, (void*)qhd);   // Q, scaled
    hipLaunchKernelGGL((gemm_kernel<1,1,0>), ggrid, dim3(256), 0, stream,
                       (const void*)k, wkt, bk, (void*)khd);   // K
    hipLaunchKernelGGL((gemm_kernel<1,2,0>), ggrid, dim3(256), 0, stream,
                       (const void*)v, wvt, bv, (void*)vtd);   // V -> V^T layout

    hipLaunchKernelGGL(attn_kernel, dim3(SEQ/128, BATCH*NHEADS), dim3(512), 0, stream,
                       qhd, khd, vtd, xat);

    hipLaunchKernelGGL((gemm_kernel<0,0,0>), ggrid, dim3(256), 0, stream,
                       (const void*)xat, wot, bo, d_out);
}